// Round 2
// baseline (620.630 us; speedup 1.0000x reference)
//
#include <hip/hip_runtime.h>
#include <stdint.h>

// BridgeoutFcLayer forward, training path.
// out[b,o] = sum_i x[b,i] * (w[i,o] + |w[i,o]|*noise[b,i,o]) + bias[o]
// noise = bernoulli(key(42), 0.5)/0.5 - 1 in {+1,-1}
//
// JAX >= 0.4.36 defaults jax_threefry_partitionable=True:
//   counts = iota(uint64, n); per element i:
//     (b1, b2) = threefry2x32(key=(0,42), hi=i>>32, lo=i&0xffffffff)
//     bits     = b1 ^ b2            (bit_width == 32 path)
// n = 2^28 < 2^32 so hi == 0 for all elements.
// uniform = f32((bits>>9)|0x3F800000) - 1;  keep = uniform < 0.5  <=> MSB(bits)==0
// w_eff = w + |w|*(keep ? +1 : -1) = w + sign_inject(MSB(bits), |w|)

#define TF_ROUND(r)                                  \
  {                                                  \
    v0 += v1;                                        \
    v1 = ((v1 << (r)) | (v1 >> (32 - (r))));         \
    v1 ^= v0;                                        \
  }

// threefry2x32 with key (0, 42), counter (0, c); returns word0 ^ word1.
__device__ __forceinline__ uint32_t tf_bits_0_42(uint32_t c) {
  const uint32_t KS1 = 42u;
  const uint32_t KS2 = 0x1BD11BF0u;  // 0 ^ 42 ^ 0x1BD11BDA

  uint32_t v0 = 0u;        // x1(=hi=0) + ks0(=0)
  uint32_t v1 = c + KS1;   // x2(=lo)   + ks1

  TF_ROUND(13) TF_ROUND(15) TF_ROUND(26) TF_ROUND(6)
  v0 += KS1;               v1 += KS2 + 1u;
  TF_ROUND(17) TF_ROUND(29) TF_ROUND(16) TF_ROUND(24)
  v0 += KS2;               v1 += 2u;            // + ks0 + 2
  TF_ROUND(13) TF_ROUND(15) TF_ROUND(26) TF_ROUND(6)
  /* v0 += ks0 (0) */      v1 += KS1 + 3u;
  TF_ROUND(17) TF_ROUND(29) TF_ROUND(16) TF_ROUND(24)
  v0 += KS1;               v1 += KS2 + 4u;
  TF_ROUND(13) TF_ROUND(15) TF_ROUND(26) TF_ROUND(6)
  v0 += KS2;               v1 += 5u;            // + ks0 + 5

  return v0 ^ v1;
}

__global__ __launch_bounds__(256) void BridgeoutFcLayer_60413009985793_kernel(
    const float* __restrict__ x, const float* __restrict__ weight,
    const float* __restrict__ bias, float* __restrict__ out) {
  const int oc = blockIdx.x & 3;        // which 256-wide output chunk
  const int b  = blockIdx.x >> 2;       // 0..127 (this block also does b+128)
  const int o  = (oc << 8) + threadIdx.x;

  // Stage the two x rows; per-iteration reads are wave-uniform LDS broadcasts.
  __shared__ float xs0[1024];
  __shared__ float xs1[1024];
  for (int t = threadIdx.x; t < 1024; t += 256) {
    xs0[t] = x[t + (b << 10)];
    xs1[t] = x[t + ((b + 128) << 10)];
  }
  __syncthreads();

  float acc0 = 0.0f, acc1 = 0.0f;
  const uint32_t idx0_base = ((uint32_t)b << 20) + (uint32_t)o;  // (b, 0, o)

#pragma unroll 4
  for (int i = 0; i < 1024; ++i) {
    float w = weight[(i << 10) + o];                 // coalesced, L2/L3-resident
    uint32_t aw = __float_as_uint(w) & 0x7FFFFFFFu;  // |w| bits

    uint32_t c0 = idx0_base + ((uint32_t)i << 10);
    uint32_t bits0 = tf_bits_0_42(c0);                // element (b,   i, o)
    uint32_t bits1 = tf_bits_0_42(c0 + 0x08000000u);  // element (b+128,i, o)

    // MSB==0 -> keep -> +|w|; MSB==1 -> drop -> -|w|
    float pert0 = __uint_as_float((bits0 & 0x80000000u) | aw);
    float pert1 = __uint_as_float((bits1 & 0x80000000u) | aw);

    acc0 = fmaf(xs0[i], w + pert0, acc0);
    acc1 = fmaf(xs1[i], w + pert1, acc1);
  }

  float bo = bias[o];
  out[(b << 10) + o]          = acc0 + bo;
  out[((b + 128) << 10) + o]  = acc1 + bo;
}

extern "C" void kernel_launch(void* const* d_in, const int* in_sizes, int n_in,
                              void* d_out, int out_size, void* d_ws, size_t ws_size,
                              hipStream_t stream) {
  const float* x      = (const float*)d_in[0];
  const float* weight = (const float*)d_in[1];
  const float* bias   = (const float*)d_in[2];
  float* out          = (float*)d_out;

  // 128 b-pairs x 4 o-chunks = 512 blocks of 256 threads
  BridgeoutFcLayer_60413009985793_kernel<<<512, 256, 0, stream>>>(x, weight, bias, out);
}

// Round 3
// 469.065 us; speedup vs baseline: 1.3231x; 1.3231x over previous
//
#include <hip/hip_runtime.h>
#include <stdint.h>

// BridgeoutFcLayer forward, training path. Bit-exact vs JAX with
// jax_threefry_partitionable=True (verified: absmax 0.0 in R2):
//   per element i (linear idx over (256,1024,1024)):
//     (b1,b2) = threefry2x32(key=(0,42), hi=0, lo=i);  bits = b1 ^ b2
//     keep <=> MSB(bits)==0
//   w_eff = w + |w|*(keep?+1:-1) = sign_inject(MSB(bits), |w|) + w
//
// VALU-bound kernel: rotates forced to v_alignbit_b32 (1 op), sign-inject
// as the v_bfi_b32 pattern, counters strength-reduced to one literal add
// per hash.

__device__ __forceinline__ uint32_t rotl_ab(uint32_t x, uint32_t r) {
  // rotl(x,r) == rotr(x,32-r) == v_alignbit_b32(x, x, 32-r)
  return __builtin_amdgcn_alignbit(x, x, 32u - r);
}

#define TF_R(r)            \
  {                        \
    v0 += v1;              \
    v1 = rotl_ab(v1, r);   \
    v1 ^= v0;              \
  }

// threefry2x32, key (0,42), counter (0,c); returns word0 ^ word1.
__device__ __forceinline__ uint32_t tf_bits_0_42(uint32_t c) {
  const uint32_t KS1 = 42u;
  const uint32_t KS2 = 0x1BD11BF0u;  // 0 ^ 42 ^ 0x1BD11BDA

  uint32_t v1 = c + KS1;   // x2(lo) + ks1
  uint32_t v0 = v1;        // round 1: v0 = 0 + v1
  v1 = rotl_ab(v1, 13) ^ v0;
  TF_R(15) TF_R(26) TF_R(6)
  v0 += KS1;               v1 += KS2 + 1u;
  TF_R(17) TF_R(29) TF_R(16) TF_R(24)
  v0 += KS2;               v1 += 2u;            // + ks0 + 2
  TF_R(13) TF_R(15) TF_R(26) TF_R(6)
  /* v0 += ks0 (0) */      v1 += KS1 + 3u;
  TF_R(17) TF_R(29) TF_R(16) TF_R(24)
  v0 += KS1;               v1 += KS2 + 4u;
  TF_R(13) TF_R(15) TF_R(26) TF_R(6)
  v0 += KS2;               v1 += 5u;            // + ks0 + 5

  return v0 ^ v1;
}

// pert = sign(bits) | |w|  — exact v_bfi_b32 pattern: (S0&S1)|(~S0&S2)
__device__ __forceinline__ float sign_inject(uint32_t bits, float w) {
  uint32_t r = (bits & 0x80000000u) | (__float_as_uint(w) & 0x7FFFFFFFu);
  return __uint_as_float(r);
}

__global__ __launch_bounds__(256) void BridgeoutFcLayer_60413009985793_kernel(
    const float* __restrict__ x, const float* __restrict__ weight,
    const float* __restrict__ bias, float* __restrict__ out) {
  const int oc = blockIdx.x & 3;        // 256-wide output chunk
  const int b  = blockIdx.x >> 2;       // 0..127 (block also does b+128)
  const int o  = (oc << 8) + threadIdx.x;

  __shared__ float xs0[1024];
  __shared__ float xs1[1024];
  for (int t = threadIdx.x; t < 1024; t += 256) {
    xs0[t] = x[t + (b << 10)];
    xs1[t] = x[t + ((b + 128) << 10)];
  }
  __syncthreads();

  float acc0 = 0.0f, acc1 = 0.0f;
  uint32_t cbase = ((uint32_t)b << 20) + (uint32_t)o;  // element (b, 0, o)
  const float* wp = weight + o;

#pragma unroll 2
  for (int i = 0; i < 1024; i += 4) {
    // 4 unrolled K-steps; counters are cbase + {0,1,2,3}*1024 (literal folds)
#pragma unroll 4
    for (int u = 0; u < 4; ++u) {
      float w = wp[u << 10];
      uint32_t bits0 = tf_bits_0_42(cbase + (u << 10));                 // (b,    i+u, o)
      uint32_t bits1 = tf_bits_0_42(cbase + (u << 10) + 0x08000000u);   // (b+128,i+u, o)
      acc0 = fmaf(xs0[i + u], w + sign_inject(bits0, w), acc0);
      acc1 = fmaf(xs1[i + u], w + sign_inject(bits1, w), acc1);
    }
    cbase += 4096u;
    wp += 4096;
  }

  float bo = bias[o];
  out[(b << 10) + o]         = acc0 + bo;
  out[((b + 128) << 10) + o] = acc1 + bo;
}

extern "C" void kernel_launch(void* const* d_in, const int* in_sizes, int n_in,
                              void* d_out, int out_size, void* d_ws, size_t ws_size,
                              hipStream_t stream) {
  const float* x      = (const float*)d_in[0];
  const float* weight = (const float*)d_in[1];
  const float* bias   = (const float*)d_in[2];
  float* out          = (float*)d_out;

  BridgeoutFcLayer_60413009985793_kernel<<<512, 256, 0, stream>>>(x, weight, bias, out);
}